// Round 7
// baseline (159.715 us; speedup 1.0000x reference)
//
#include <hip/hip_runtime.h>

// Fusion_loss: 3 modalities of Mahalanobis-distance softmax fusion.
// K=64 classes, Q=128 queries/class, DIM=1024. Rows M = 8192.
// logits_m[r][c] = -(||x_r||^2 - 2 x_r.p_c + ||p_c||^2) / var_c
// loss = mean_r sum_m w_m * (lse_m(r) - logits_m[r][y_r]),  y_r = r/128
// acc  = mean_r [argmax_c sum_m w_m softmax(logits_m)[r][c] == y_r]
//
// R7: single fused main kernel. R6's K-split cost a 12.6 MB pd round-trip
// + a 512-block softmax pass. Now: block = 12 waves (3 m x 4 col-groups)
// x 16 rows x full K; A staged per-modality via global_load_lds chunks
// (3 x 16.6 KB tiles, UW=260 conflict-free); complete fused softmax +
// loss + argmax in-block (cross-wave via LDS); only 512 (loss,cnt) pairs
// leave the block. Grid 512 = exactly 2 blocks/CU (24 waves, LDS 56KBx2).
// 48 KB DMA in flight per block per chunk >> 9 KB Little's-law need.

typedef _Float16 half8 __attribute__((ext_vector_type(8)));
typedef float    floatx4 __attribute__((ext_vector_type(4)));

#define NCLS   64
#define QPC    128
#define DIM    1024
#define NROWS  (NCLS * QPC)      // 8192
#define NRT    (NROWS / 16)      // 512 row tiles
#define UW     260               // LDS row stride in words (1040 B), 260%32=4

// ws layout
#define OFF_W     0                           // f16 protos, B-frag units
#define W_BYTES   (3 * NCLS * DIM * 2)        // 393216
#define OFF_P2    W_BYTES                     // 768 B
#define OFF_PART  394240                      // aligned
#define WS_NEED   (OFF_PART + NRT * 8)

__device__ __forceinline__ void dma16(const float* g, float* l) {
    __builtin_amdgcn_global_load_lds(
        (const __attribute__((address_space(1))) void*)g,
        (__attribute__((address_space(3))) void*)l,
        16, 0, 0);
}

// ---------------- prep: protos -> f16 B-frag layout + p2 ----------------
// Unit (m,kcg,t) = 1KB: lane (l15,quad) holds 8 halves = col t*16+l15,
// k = kcg*32 + quad*8 .. +8.  p2[m*64+c] via atomics.
__global__ __launch_bounds__(64) void prep_protos(
    const float* __restrict__ Ptf, const float* __restrict__ Pde,
    const float* __restrict__ Pff, _Float16* __restrict__ W,
    float* __restrict__ p2)
{
    const int m    = blockIdx.x >> 5;
    const int kcg  = blockIdx.x & 31;
    const int lane = threadIdx.x;
    const int l15  = lane & 15;
    const int quad = lane >> 4;
    const float* __restrict__ P = (m == 0) ? Ptf : (m == 1) ? Pde : Pff;

    #pragma unroll
    for (int t = 0; t < 4; ++t) {
        const float* src = P + (size_t)(t * 16 + l15) * DIM + kcg * 32 + quad * 8;
        const float4 b0 = *reinterpret_cast<const float4*>(src);
        const float4 b1 = *reinterpret_cast<const float4*>(src + 4);
        half8 h;
        h[0] = (_Float16)b0.x; h[1] = (_Float16)b0.y;
        h[2] = (_Float16)b0.z; h[3] = (_Float16)b0.w;
        h[4] = (_Float16)b1.x; h[5] = (_Float16)b1.y;
        h[6] = (_Float16)b1.z; h[7] = (_Float16)b1.w;
        *reinterpret_cast<half8*>(W + ((size_t)(m * 32 + kcg) * 4 + t) * 512 + lane * 8) = h;

        float s = b0.x*b0.x + b0.y*b0.y + b0.z*b0.z + b0.w*b0.w
                + b1.x*b1.x + b1.y*b1.y + b1.z*b1.z + b1.w*b1.w;
        s += __shfl_xor(s, 16);
        s += __shfl_xor(s, 32);
        if (quad == 0) atomicAdd(&p2[m * 64 + t * 16 + l15], s);
    }
}

// ---------------- main: fully fused, DMA-staged, one block per row-tile ----
// 12 waves: wave = (m, t); wave owns modality m, cols t*16..t*16+15, 16 rows.
__global__ __launch_bounds__(768, 6) void fusion_main(
    const float* __restrict__ Xtf, const float* __restrict__ Vtf,
    const float* __restrict__ Xde, const float* __restrict__ Vde,
    const float* __restrict__ Xff, const float* __restrict__ Vff,
    const _Float16* __restrict__ W, const float* __restrict__ p2g,
    float2* __restrict__ partial)
{
    __shared__ float tiles[3][16 * UW];   // 49,920 B (DMA-only writes)
    __shared__ float x2s[3][16];
    __shared__ float mxW[12][16];
    __shared__ float sW[12][16];
    __shared__ float predL[16 * 65];      // 4160 B, +1 pad per row
    __shared__ float lossL;

    const int tid  = threadIdx.x;
    const int wave = tid >> 6;        // 0..11
    const int lane = tid & 63;
    const int l15  = lane & 15;
    const int quad = lane >> 4;       // 0..3
    const int m    = wave >> 2;       // modality
    const int t    = wave & 3;        // col-group
    const int rowBase = blockIdx.x * 16;

    for (int i = tid; i < 16 * 65; i += 768) predL[i] = 0.0f;
    if (tid == 0) lossL = 0.0f;

    const float* __restrict__ X = (m == 0) ? Xtf : (m == 1) ? Xde : Xff;
    const float* __restrict__ V = (m == 0) ? Vtf : (m == 1) ? Vde : Vff;
    const float  wgt = (m == 0) ? 1.0f : (m == 1) ? 0.8f : 0.6f;

    floatx4 d = (floatx4){0.f, 0.f, 0.f, 0.f};
    float x2p = 0.0f;

    #pragma unroll 1
    for (int c = 0; c < 4; ++c) {
        if (c) __syncthreads();   // prev chunk fully consumed before overwrite
        // wave (m,t) stages rows t*4..t*4+3 of modality-m tile (1 KB each,
        // lane-contiguous: HW scatters lane i to base + i*16)
        const float* gb = X + (size_t)(rowBase + t * 4) * DIM + c * 256 + lane * 4;
        #pragma unroll
        for (int r4 = 0; r4 < 4; ++r4)
            dma16(gb + (size_t)r4 * DIM, &tiles[m][(t * 4 + r4) * UW]);
        __syncthreads();          // drains vmcnt(0): DMA visible

        #pragma unroll
        for (int kc = 0; kc < 8; ++kc) {
            const int off = l15 * UW + kc * 32 + quad * 8;
            const float4 a0 = *reinterpret_cast<const float4*>(&tiles[m][off]);
            const float4 a1 = *reinterpret_cast<const float4*>(&tiles[m][off + 4]);
            const half8 bf = *reinterpret_cast<const half8*>(
                W + ((size_t)(m * 32 + c * 8 + kc) * 4 + t) * 512 + lane * 8);

            if (t == 0)   // one wave per modality computes x2 (shared later)
                x2p += a0.x*a0.x + a0.y*a0.y + a0.z*a0.z + a0.w*a0.w
                     + a1.x*a1.x + a1.y*a1.y + a1.z*a1.z + a1.w*a1.w;

            half8 af;
            af[0] = (_Float16)a0.x; af[1] = (_Float16)a0.y;
            af[2] = (_Float16)a0.z; af[3] = (_Float16)a0.w;
            af[4] = (_Float16)a1.x; af[5] = (_Float16)a1.y;
            af[6] = (_Float16)a1.z; af[7] = (_Float16)a1.w;

            d = __builtin_amdgcn_mfma_f32_16x16x32_f16(af, bf, d, 0, 0, 0);
        }
    }

    // x2 of row l15: t==0 wave reduces quad slices, shares via LDS
    if (t == 0) {
        x2p += __shfl_xor(x2p, 16);
        x2p += __shfl_xor(x2p, 32);
        if (quad == 0) x2s[m][l15] = x2p;
    }
    __syncthreads();

    // logits: row = quad*4+r, col = t*16+l15 (MFMA C/D layout)
    const int col = t * 16 + l15;
    const float vc  = V[col];
    const float p2c = p2g[m * 64 + col];
    float lg[4];
    #pragma unroll
    for (int r = 0; r < 4; ++r)
        lg[r] = (2.0f * d[r] - x2s[m][quad * 4 + r] - p2c) / vc;

    // per-wave 16-col max per row -> LDS
    #pragma unroll
    for (int r = 0; r < 4; ++r) {
        float mx = lg[r];
        #pragma unroll
        for (int dl = 1; dl <= 8; dl <<= 1) mx = fmaxf(mx, __shfl_xor(mx, dl));
        if (l15 == 0) mxW[wave][quad * 4 + r] = mx;
    }
    __syncthreads();

    // global (m,row) max, per-wave exp-sum -> LDS
    float gmx[4];
    #pragma unroll
    for (int r = 0; r < 4; ++r) {
        const int row = quad * 4 + r;
        gmx[r] = fmaxf(fmaxf(mxW[m * 4 + 0][row], mxW[m * 4 + 1][row]),
                       fmaxf(mxW[m * 4 + 2][row], mxW[m * 4 + 3][row]));
        float s = expf(lg[r] - gmx[r]);
        #pragma unroll
        for (int dl = 1; dl <= 8; dl <<= 1) s += __shfl_xor(s, dl);
        if (l15 == 0) sW[wave][quad * 4 + r] = s;
    }
    __syncthreads();

    // lse per (m,row); loss at target col; fused pred via LDS atomics
    const int y = rowBase >> 7;   // target class, uniform across block
    float lossAcc = 0.0f;
    #pragma unroll
    for (int r = 0; r < 4; ++r) {
        const int row = quad * 4 + r;
        const float lse = gmx[r] + logf(sW[m * 4 + 0][row] + sW[m * 4 + 1][row]
                                      + sW[m * 4 + 2][row] + sW[m * 4 + 3][row]);
        if (col == y) lossAcc += wgt * (lse - lg[r]);
        atomicAdd(&predL[row * 65 + col], wgt * expf(lg[r] - lse));
    }
    #pragma unroll
    for (int dl = 1; dl <= 32; dl <<= 1) lossAcc += __shfl_xor(lossAcc, dl);
    if (lane == 0) atomicAdd(&lossL, lossAcc);
    __syncthreads();

    if (wave == 0) {
        // fused argmax per row; first-max tie-break = lowest col
        float cnt = 0.0f;
        #pragma unroll 1
        for (int r = 0; r < 16; ++r) {
            float bv = predL[r * 65 + lane];
            int   bc = lane;
            #pragma unroll
            for (int dl = 1; dl <= 32; dl <<= 1) {
                const float ov = __shfl_xor(bv, dl);
                const int   oc = __shfl_xor(bc, dl);
                if (ov > bv || (ov == bv && oc < bc)) { bv = ov; bc = oc; }
            }
            if (lane == 0 && bc == y) cnt += 1.0f;
        }
        if (lane == 0) partial[blockIdx.x] = make_float2(lossL, cnt);
    }
}

// ---------------- finalize: reduce 512 per-block partials ----------------
__global__ __launch_bounds__(256) void finalize(
    const float2* __restrict__ partial, float* __restrict__ out)
{
    const int tid  = threadIdx.x;
    const int lane = tid & 63;
    const int v    = tid >> 6;
    float l = 0.0f, c = 0.0f;
    for (int i = tid; i < NRT; i += 256) {
        const float2 p = partial[i];
        l += p.x; c += p.y;
    }
    #pragma unroll
    for (int dl = 1; dl <= 32; dl <<= 1) {
        l += __shfl_xor(l, dl);
        c += __shfl_xor(c, dl);
    }
    __shared__ float sl[4], sc[4];
    if (lane == 0) { sl[v] = l; sc[v] = c; }
    __syncthreads();
    if (tid == 0) {
        out[0] = (sl[0] + sl[1] + sl[2] + sl[3]) * (1.0f / NROWS);
        out[1] = (sc[0] + sc[1] + sc[2] + sc[3]) * (1.0f / NROWS);
    }
}

// ---------------- fallback (R2 kernel, used only if ws too small) --------
#define NWAVES 12
#define KSPLIT 4
#define KSLICE (DIM / KSPLIT)
#define NITER  (KSLICE / 32)
#define DSTRIDE 17
#define PSTRIDE 65

__global__ __launch_bounds__(NWAVES * 64) void fusion_loss_fallback(
    const float* __restrict__ Xtf, const float* __restrict__ Ptf, const float* __restrict__ Vtf,
    const float* __restrict__ Xde, const float* __restrict__ Pde, const float* __restrict__ Vde,
    const float* __restrict__ Xff, const float* __restrict__ Pff, const float* __restrict__ Vff,
    float* __restrict__ out)
{
    __shared__ float dpart[NWAVES][64 * DSTRIDE];
    __shared__ float x2part[NWAVES][16];
    __shared__ float p2part[NWAVES][64];
    __shared__ float predL[16 * PSTRIDE];
    __shared__ float lossL;

    const int tid  = threadIdx.x;
    const int wave = tid >> 6;
    const int lane = tid & 63;
    const int l15  = lane & 15;
    const int quad = lane >> 4;
    const int m    = wave >> 2;
    const int kq   = wave & 3;
    const int rowBase = blockIdx.x * 16;

    for (int i = tid; i < 16 * PSTRIDE; i += NWAVES * 64) predL[i] = 0.0f;
    if (tid == 0) lossL = 0.0f;

    const float* __restrict__ X = (m == 0) ? Xtf : (m == 1) ? Xde : Xff;
    const float* __restrict__ P = (m == 0) ? Ptf : (m == 1) ? Pde : Pff;
    const float* __restrict__ V = (m == 0) ? Vtf : (m == 1) ? Vde : Vff;
    const float  w = (m == 0) ? 1.0f : (m == 1) ? 0.8f : 0.6f;

    floatx4 d[4];
    #pragma unroll
    for (int t = 0; t < 4; ++t) d[t] = (floatx4){0.f, 0.f, 0.f, 0.f};
    float x2p    = 0.0f;
    float p2p[4] = {0.f, 0.f, 0.f, 0.f};

    const float* xrow = X + (size_t)(rowBase + l15) * DIM + kq * KSLICE + quad * 8;
    const float* prow[4];
    #pragma unroll
    for (int t = 0; t < 4; ++t)
        prow[t] = P + (size_t)(t * 16 + l15) * DIM + kq * KSLICE + quad * 8;

    #pragma unroll 2
    for (int kc = 0; kc < NITER; ++kc) {
        const int ko = kc * 32;
        const float4 a0 = *reinterpret_cast<const float4*>(xrow + ko);
        const float4 a1 = *reinterpret_cast<const float4*>(xrow + ko + 4);
        float4 b0[4], b1[4];
        #pragma unroll
        for (int t = 0; t < 4; ++t) {
            b0[t] = *reinterpret_cast<const float4*>(prow[t] + ko);
            b1[t] = *reinterpret_cast<const float4*>(prow[t] + ko + 4);
        }
        x2p += a0.x*a0.x + a0.y*a0.y + a0.z*a0.z + a0.w*a0.w
             + a1.x*a1.x + a1.y*a1.y + a1.z*a1.z + a1.w*a1.w;
        half8 af;
        af[0] = (_Float16)a0.x; af[1] = (_Float16)a0.y;
        af[2] = (_Float16)a0.z; af[3] = (_Float16)a0.w;
        af[4] = (_Float16)a1.x; af[5] = (_Float16)a1.y;
        af[6] = (_Float16)a1.z; af[7] = (_Float16)a1.w;
        #pragma unroll
        for (int t = 0; t < 4; ++t) {
            p2p[t] += b0[t].x*b0[t].x + b0[t].y*b0[t].y + b0[t].z*b0[t].z + b0[t].w*b0[t].w
                    + b1[t].x*b1[t].x + b1[t].y*b1[t].y + b1[t].z*b1[t].z + b1[t].w*b1[t].w;
            half8 bf;
            bf[0] = (_Float16)b0[t].x; bf[1] = (_Float16)b0[t].y;
            bf[2] = (_Float16)b0[t].z; bf[3] = (_Float16)b0[t].w;
            bf[4] = (_Float16)b1[t].x; bf[5] = (_Float16)b1[t].y;
            bf[6] = (_Float16)b1[t].z; bf[7] = (_Float16)b1[t].w;
            d[t] = __builtin_amdgcn_mfma_f32_16x16x32_f16(af, bf, d[t], 0, 0, 0);
        }
    }

    x2p += __shfl_xor(x2p, 16);
    x2p += __shfl_xor(x2p, 32);
    #pragma unroll
    for (int t = 0; t < 4; ++t) {
        p2p[t] += __shfl_xor(p2p[t], 16);
        p2p[t] += __shfl_xor(p2p[t], 32);
    }
    {
        float* dp = &dpart[wave][lane * DSTRIDE];
        #pragma unroll
        for (int t = 0; t < 4; ++t)
            *reinterpret_cast<float4*>(dp + t * 4) =
                make_float4(d[t][0], d[t][1], d[t][2], d[t][3]);
        if (quad == 0) {
            x2part[wave][l15] = x2p;
            #pragma unroll
            for (int t = 0; t < 4; ++t) p2part[wave][t * 16 + l15] = p2p[t];
        }
    }
    __syncthreads();

    const int y = rowBase >> 7;

    if (kq == 0) {
        floatx4 dsum[4];
        #pragma unroll
        for (int t = 0; t < 4; ++t) dsum[t] = (floatx4){0.f, 0.f, 0.f, 0.f};
        float x2r[4] = {0.f, 0.f, 0.f, 0.f};
        float p2c[4] = {0.f, 0.f, 0.f, 0.f};
        #pragma unroll
        for (int k2 = 0; k2 < KSPLIT; ++k2) {
            const int wv = m * 4 + k2;
            const float* src = &dpart[wv][lane * DSTRIDE];
            #pragma unroll
            for (int t = 0; t < 4; ++t) {
                const float4 vv = *reinterpret_cast<const float4*>(src + t * 4);
                dsum[t][0] += vv.x; dsum[t][1] += vv.y; dsum[t][2] += vv.z; dsum[t][3] += vv.w;
            }
            #pragma unroll
            for (int r = 0; r < 4; ++r) x2r[r] += x2part[wv][quad * 4 + r];
            #pragma unroll
            for (int t = 0; t < 4; ++t) p2c[t] += p2part[wv][t * 16 + l15];
        }
        float vc[4];
        #pragma unroll
        for (int t = 0; t < 4; ++t) vc[t] = V[t * 16 + l15];

        float lossAcc = 0.0f;
        #pragma unroll
        for (int r = 0; r < 4; ++r) {
            float lg[4];
            #pragma unroll
            for (int t = 0; t < 4; ++t)
                lg[t] = (2.0f * dsum[t][r] - x2r[r] - p2c[t]) / vc[t];
            float mx = fmaxf(fmaxf(lg[0], lg[1]), fmaxf(lg[2], lg[3]));
            #pragma unroll
            for (int dl = 1; dl <= 8; dl <<= 1) mx = fmaxf(mx, __shfl_xor(mx, dl));
            float s = expf(lg[0] - mx) + expf(lg[1] - mx)
                    + expf(lg[2] - mx) + expf(lg[3] - mx);
            #pragma unroll
            for (int dl = 1; dl <= 8; dl <<= 1) s += __shfl_xor(s, dl);
            const float lse = mx + logf(s);
            const int row = quad * 4 + r;
            #pragma unroll
            for (int t = 0; t < 4; ++t) {
                const int colc = t * 16 + l15;
                if (colc == y) lossAcc += w * (lse - lg[t]);
                atomicAdd(&predL[row * PSTRIDE + colc], w * expf(lg[t] - lse));
            }
        }
        #pragma unroll
        for (int dl = 1; dl <= 32; dl <<= 1) lossAcc += __shfl_xor(lossAcc, dl);
        if (lane == 0) atomicAdd(&lossL, lossAcc);
    }
    __syncthreads();

    if (wave == 0) {
        float cnt = 0.0f;
        #pragma unroll 1
        for (int r = 0; r < 16; ++r) {
            float bv = predL[r * PSTRIDE + lane];
            int   bc = lane;
            #pragma unroll
            for (int dl = 1; dl <= 32; dl <<= 1) {
                const float ov = __shfl_xor(bv, dl);
                const int   oc = __shfl_xor(bc, dl);
                if (ov > bv || (ov == bv && oc < bc)) { bv = ov; bc = oc; }
            }
            if (lane == 0 && bc == y) cnt += 1.0f;
        }
        if (lane == 0) {
            atomicAdd(&out[0], lossL * (1.0f / NROWS));
            atomicAdd(&out[1], cnt * (1.0f / NROWS));
        }
    }
}

extern "C" void kernel_launch(void* const* d_in, const int* in_sizes, int n_in,
                              void* d_out, int out_size, void* d_ws, size_t ws_size,
                              hipStream_t stream) {
    const float* Xtf = (const float*)d_in[0];
    const float* Ptf = (const float*)d_in[1];
    const float* Vtf = (const float*)d_in[2];
    const float* Xde = (const float*)d_in[3];
    const float* Pde = (const float*)d_in[4];
    const float* Vde = (const float*)d_in[5];
    const float* Xff = (const float*)d_in[6];
    const float* Pff = (const float*)d_in[7];
    const float* Vff = (const float*)d_in[8];
    float* out = (float*)d_out;

    if (ws_size >= (size_t)WS_NEED) {
        char* ws = (char*)d_ws;
        _Float16* W    = (_Float16*)(ws + OFF_W);
        float*    p2   = (float*)(ws + OFF_P2);
        float2*   part = (float2*)(ws + OFF_PART);

        hipMemsetAsync(p2, 0, 3 * NCLS * sizeof(float), stream);
        prep_protos<<<dim3(96), dim3(64), 0, stream>>>(Ptf, Pde, Pff, W, p2);
        fusion_main<<<dim3(NRT), dim3(768), 0, stream>>>(
            Xtf, Vtf, Xde, Vde, Xff, Vff, W, p2, part);
        finalize<<<dim3(1), dim3(256), 0, stream>>>(part, out);
    } else {
        hipMemsetAsync(out, 0, 2 * sizeof(float), stream);
        fusion_loss_fallback<<<dim3(NROWS / 16), dim3(NWAVES * 64), 0, stream>>>(
            Xtf, Ptf, Vtf, Xde, Pde, Vde, Xff, Pff, Vff, out);
    }
}

// Round 8
// 156.770 us; speedup vs baseline: 1.0188x; 1.0188x over previous
//
#include <hip/hip_runtime.h>

// Fusion_loss: 3 modalities of Mahalanobis-distance softmax fusion.
// K=64 classes, Q=128 queries/class, DIM=1024. Rows M = 8192.
// logits_m[r][c] = -(||x_r||^2 - 2 x_r.p_c + ||p_c||^2) / var_c
// loss = mean_r sum_m w_m * (lse_m(r) - logits_m[r][y_r]),  y_r = r/128
// acc  = mean_r [argmax_c sum_m w_m softmax(logits_m)[r][c] == y_r]
//
// R8: R6 main (small 4-wave blocks, 8/CU — beat R7's 12-wave blocks) +
// double-buffered DMA prefetch (R6/R7 never overlapped DMA with compute:
// barrier;DMA;barrier;compute). Now: stage(c+1) issued right after the
// drain barrier, before compute(c) — one barrier/chunk, m97-style.
// Chunks = 128 cols (4 per K-half), dbuf 2x8.4KB = 16.9KB -> 8 blk/CU.
// Bank conflicts (4 cyc/b128, structural for 16B-aligned strides) accepted.

typedef _Float16 half8 __attribute__((ext_vector_type(8)));
typedef float    floatx4 __attribute__((ext_vector_type(4)));

#define NCLS   64
#define QPC    128
#define DIM    1024
#define NROWS  (NCLS * QPC)      // 8192
#define NRT    (NROWS / 16)      // 512 row tiles
#define UW2    132               // LDS row stride in words for 128-col chunk

// ws layout
#define OFF_W     0                           // f16 protos, B-frag units
#define W_BYTES   (3 * NCLS * DIM * 2)        // 393216
#define OFF_P2    W_BYTES                     // 768 B
#define OFF_PD    397312                      // 4K-aligned
#define PD_BYTES  (3 * NRT * 2 * 16 * 64 * 4) // 12582912
#define OFF_PX2   (OFF_PD + PD_BYTES)
#define PX2_BYTES (3 * NRT * 2 * 16 * 4)      // 196608
#define OFF_LP    (OFF_PX2 + PX2_BYTES)       // 512 floats
#define OFF_CP    (OFF_LP + NRT * 4)          // 512 floats
#define WS_NEED   (OFF_CP + NRT * 4)

__device__ __forceinline__ void dma4(const float* g, float* l) {
    __builtin_amdgcn_global_load_lds(
        (const __attribute__((address_space(1))) void*)g,
        (__attribute__((address_space(3))) void*)l,
        4, 0, 0);
}

// ---------------- prep: protos -> f16 B-frag layout + p2 ----------------
__global__ __launch_bounds__(64) void prep_protos(
    const float* __restrict__ Ptf, const float* __restrict__ Pde,
    const float* __restrict__ Pff, _Float16* __restrict__ W,
    float* __restrict__ p2)
{
    const int m    = blockIdx.x >> 5;
    const int kcg  = blockIdx.x & 31;
    const int lane = threadIdx.x;
    const int l15  = lane & 15;
    const int quad = lane >> 4;
    const float* __restrict__ P = (m == 0) ? Ptf : (m == 1) ? Pde : Pff;

    #pragma unroll
    for (int t = 0; t < 4; ++t) {
        const float* src = P + (size_t)(t * 16 + l15) * DIM + kcg * 32 + quad * 8;
        const float4 b0 = *reinterpret_cast<const float4*>(src);
        const float4 b1 = *reinterpret_cast<const float4*>(src + 4);
        half8 h;
        h[0] = (_Float16)b0.x; h[1] = (_Float16)b0.y;
        h[2] = (_Float16)b0.z; h[3] = (_Float16)b0.w;
        h[4] = (_Float16)b1.x; h[5] = (_Float16)b1.y;
        h[6] = (_Float16)b1.z; h[7] = (_Float16)b1.w;
        *reinterpret_cast<half8*>(W + ((size_t)(m * 32 + kcg) * 4 + t) * 512 + lane * 8) = h;

        float s = b0.x*b0.x + b0.y*b0.y + b0.z*b0.z + b0.w*b0.w
                + b1.x*b1.x + b1.y*b1.y + b1.z*b1.z + b1.w*b1.w;
        s += __shfl_xor(s, 16);
        s += __shfl_xor(s, 32);
        if (quad == 0) atomicAdd(&p2[m * 64 + t * 16 + l15], s);
    }
}

// ---------------- main: K-split partial GEMM, double-buffered DMA ----------
// block = (m, row-tile, ks); 4 waves; wave w = 16 rows x cols w*16..+15.
__global__ __launch_bounds__(256, 8) void fusion_main(
    const float* __restrict__ Xtf, const float* __restrict__ Xde,
    const float* __restrict__ Xff, const _Float16* __restrict__ W,
    float* __restrict__ pd, float* __restrict__ px2)
{
    __shared__ float buf[2][16 * UW2];   // 16,896 B total (DMA-only writes)

    const int tid  = threadIdx.x;
    const int w    = tid >> 6;
    const int lane = tid & 63;
    const int l15  = lane & 15;
    const int quad = lane >> 4;
    const int b    = blockIdx.x;
    const int m    = b >> 10;         // /(512*2)
    const int rt   = (b & 1023) >> 1;
    const int ks   = b & 1;
    const int rowBase = rt * 16;

    const float* __restrict__ X = (m == 0) ? Xtf : (m == 1) ? Xde : Xff;

    // per-lane global base for this wave's 4 rows, chunk c adds c*128
    const float* gb = X + (size_t)(rowBase + w * 4) * DIM + ks * 512 + lane;

    floatx4 d = (floatx4){0.f, 0.f, 0.f, 0.f};
    float x2p = 0.0f;

    // prologue: stage chunk 0 into buf[0]
    #pragma unroll
    for (int r4 = 0; r4 < 4; ++r4) {
        dma4(gb + (size_t)r4 * DIM,      &buf[0][(w * 4 + r4) * UW2]);
        dma4(gb + (size_t)r4 * DIM + 64, &buf[0][(w * 4 + r4) * UW2 + 64]);
    }

    #pragma unroll
    for (int c = 0; c < 4; ++c) {
        __syncthreads();   // drains DMA(c); all waves done with compute(c-1)
        if (c < 3) {       // prefetch chunk c+1 into the other buffer
            const float* g1 = gb + (c + 1) * 128;
            float* lb = &buf[(c + 1) & 1][0];
            #pragma unroll
            for (int r4 = 0; r4 < 4; ++r4) {
                dma4(g1 + (size_t)r4 * DIM,      lb + (w * 4 + r4) * UW2);
                dma4(g1 + (size_t)r4 * DIM + 64, lb + (w * 4 + r4) * UW2 + 64);
            }
        }
        const float* tb = &buf[c & 1][0];
        #pragma unroll
        for (int kc = 0; kc < 4; ++kc) {
            const int off = l15 * UW2 + kc * 32 + quad * 8;
            const float4 a0 = *reinterpret_cast<const float4*>(tb + off);
            const float4 a1 = *reinterpret_cast<const float4*>(tb + off + 4);
            const int kcg = ks * 16 + c * 4 + kc;
            const half8 bf = *reinterpret_cast<const half8*>(
                W + ((size_t)(m * 32 + kcg) * 4 + w) * 512 + lane * 8);

            if (w == 0)   // one wave computes x2 (rows shared by all waves)
                x2p += a0.x*a0.x + a0.y*a0.y + a0.z*a0.z + a0.w*a0.w
                     + a1.x*a1.x + a1.y*a1.y + a1.z*a1.z + a1.w*a1.w;

            half8 af;
            af[0] = (_Float16)a0.x; af[1] = (_Float16)a0.y;
            af[2] = (_Float16)a0.z; af[3] = (_Float16)a0.w;
            af[4] = (_Float16)a1.x; af[5] = (_Float16)a1.y;
            af[6] = (_Float16)a1.z; af[7] = (_Float16)a1.w;

            d = __builtin_amdgcn_mfma_f32_16x16x32_f16(af, bf, d, 0, 0, 0);
        }
    }

    // x2 of row l15 over this K-half
    const size_t tb2 = (size_t)((m * NRT + rt) * 2 + ks);
    if (w == 0) {
        x2p += __shfl_xor(x2p, 16);
        x2p += __shfl_xor(x2p, 32);
        if (quad == 0) px2[tb2 * 16 + l15] = x2p;
    }

    float* o = pd + tb2 * 1024;
    #pragma unroll
    for (int r = 0; r < 4; ++r)
        o[(quad * 4 + r) * 64 + w * 16 + l15] = d[r];   // row=quad*4+r, col
}

// ---------------- finalize1: K-combine + softmax + loss + argmax ----------
__global__ __launch_bounds__(256) void finalize1(
    const float* __restrict__ pd, const float* __restrict__ px2,
    const float* __restrict__ p2g,
    const float* __restrict__ Vtf, const float* __restrict__ Vde,
    const float* __restrict__ Vff,
    float* __restrict__ lossPart, float* __restrict__ cntPart)
{
    const int rt   = blockIdx.x;
    const int tid  = threadIdx.x;
    const int v    = tid >> 6;
    const int lane = tid & 63;

    float loss = 0.0f, cnt = 0.0f;
    #pragma unroll
    for (int r4 = 0; r4 < 4; ++r4) {
        const int row = v * 4 + r4;
        const int R   = rt * 16 + row;
        const int y   = R >> 7;
        float pf = 0.0f;
        #pragma unroll
        for (int m = 0; m < 3; ++m) {
            const size_t t0 = (size_t)((m * NRT + rt) * 2);
            const float dsum = pd[t0 * 1024 + row * 64 + lane]
                             + pd[(t0 + 1) * 1024 + row * 64 + lane];
            const float x2 = px2[t0 * 16 + row] + px2[(t0 + 1) * 16 + row];
            const float* __restrict__ V = (m == 0) ? Vtf : (m == 1) ? Vde : Vff;
            const float wgt = (m == 0) ? 1.0f : (m == 1) ? 0.8f : 0.6f;

            const float lg = (2.0f * dsum - x2 - p2g[m * 64 + lane]) / V[lane];
            float mx = lg;
            #pragma unroll
            for (int dl = 1; dl <= 32; dl <<= 1) mx = fmaxf(mx, __shfl_xor(mx, dl));
            float s = expf(lg - mx);
            #pragma unroll
            for (int dl = 1; dl <= 32; dl <<= 1) s += __shfl_xor(s, dl);
            const float lse = mx + logf(s);

            if (lane == y) loss += wgt * (lse - lg);
            pf += wgt * expf(lg - lse);
        }
        float bv = pf; int bc = lane;
        #pragma unroll
        for (int dl = 1; dl <= 32; dl <<= 1) {
            const float ov = __shfl_xor(bv, dl);
            const int   oc = __shfl_xor(bc, dl);
            if (ov > bv || (ov == bv && oc < bc)) { bv = ov; bc = oc; }
        }
        if (lane == 0 && bc == y) cnt += 1.0f;
    }

    #pragma unroll
    for (int dl = 1; dl <= 32; dl <<= 1) {
        loss += __shfl_xor(loss, dl);
        cnt  += __shfl_xor(cnt, dl);
    }
    __shared__ float sl[4], sc[4];
    if (lane == 0) { sl[v] = loss; sc[v] = cnt; }
    __syncthreads();
    if (tid == 0) {
        lossPart[rt] = sl[0] + sl[1] + sl[2] + sl[3];
        cntPart[rt]  = sc[0] + sc[1] + sc[2] + sc[3];
    }
}

// ---------------- finalize2: scalar reduce ----------------
__global__ __launch_bounds__(256) void finalize2(
    const float* __restrict__ lossPart, const float* __restrict__ cntPart,
    float* __restrict__ out)
{
    const int tid  = threadIdx.x;
    const int lane = tid & 63;
    const int v    = tid >> 6;
    float l = 0.0f, c = 0.0f;
    for (int i = tid; i < NRT; i += 256) { l += lossPart[i]; c += cntPart[i]; }
    #pragma unroll
    for (int dl = 1; dl <= 32; dl <<= 1) {
        l += __shfl_xor(l, dl);
        c += __shfl_xor(c, dl);
    }
    __shared__ float sl[4], sc[4];
    if (lane == 0) { sl[v] = l; sc[v] = c; }
    __syncthreads();
    if (tid == 0) {
        out[0] = (sl[0] + sl[1] + sl[2] + sl[3]) * (1.0f / NROWS);
        out[1] = (sc[0] + sc[1] + sc[2] + sc[3]) * (1.0f / NROWS);
    }
}

// ---------------- fallback (R2 kernel, used only if ws too small) --------
#define NWAVES 12
#define KSPLIT 4
#define KSLICE (DIM / KSPLIT)
#define NITER  (KSLICE / 32)
#define DSTRIDE 17
#define PSTRIDE 65

__global__ __launch_bounds__(NWAVES * 64) void fusion_loss_fallback(
    const float* __restrict__ Xtf, const float* __restrict__ Ptf, const float* __restrict__ Vtf,
    const float* __restrict__ Xde, const float* __restrict__ Pde, const float* __restrict__ Vde,
    const float* __restrict__ Xff, const float* __restrict__ Pff, const float* __restrict__ Vff,
    float* __restrict__ out)
{
    __shared__ float dpart[NWAVES][64 * DSTRIDE];
    __shared__ float x2part[NWAVES][16];
    __shared__ float p2part[NWAVES][64];
    __shared__ float predL[16 * PSTRIDE];
    __shared__ float lossL;

    const int tid  = threadIdx.x;
    const int wave = tid >> 6;
    const int lane = tid & 63;
    const int l15  = lane & 15;
    const int quad = lane >> 4;
    const int m    = wave >> 2;
    const int kq   = wave & 3;
    const int rowBase = blockIdx.x * 16;

    for (int i = tid; i < 16 * PSTRIDE; i += NWAVES * 64) predL[i] = 0.0f;
    if (tid == 0) lossL = 0.0f;

    const float* __restrict__ X = (m == 0) ? Xtf : (m == 1) ? Xde : Xff;
    const float* __restrict__ P = (m == 0) ? Ptf : (m == 1) ? Pde : Pff;
    const float* __restrict__ V = (m == 0) ? Vtf : (m == 1) ? Vde : Vff;
    const float  w = (m == 0) ? 1.0f : (m == 1) ? 0.8f : 0.6f;

    floatx4 d[4];
    #pragma unroll
    for (int t = 0; t < 4; ++t) d[t] = (floatx4){0.f, 0.f, 0.f, 0.f};
    float x2p    = 0.0f;
    float p2p[4] = {0.f, 0.f, 0.f, 0.f};

    const float* xrow = X + (size_t)(rowBase + l15) * DIM + kq * KSLICE + quad * 8;
    const float* prow[4];
    #pragma unroll
    for (int t = 0; t < 4; ++t)
        prow[t] = P + (size_t)(t * 16 + l15) * DIM + kq * KSLICE + quad * 8;

    #pragma unroll 2
    for (int kc = 0; kc < NITER; ++kc) {
        const int ko = kc * 32;
        const float4 a0 = *reinterpret_cast<const float4*>(xrow + ko);
        const float4 a1 = *reinterpret_cast<const float4*>(xrow + ko + 4);
        float4 b0[4], b1[4];
        #pragma unroll
        for (int t = 0; t < 4; ++t) {
            b0[t] = *reinterpret_cast<const float4*>(prow[t] + ko);
            b1[t] = *reinterpret_cast<const float4*>(prow[t] + ko + 4);
        }
        x2p += a0.x*a0.x + a0.y*a0.y + a0.z*a0.z + a0.w*a0.w
             + a1.x*a1.x + a1.y*a1.y + a1.z*a1.z + a1.w*a1.w;
        half8 af;
        af[0] = (_Float16)a0.x; af[1] = (_Float16)a0.y;
        af[2] = (_Float16)a0.z; af[3] = (_Float16)a0.w;
        af[4] = (_Float16)a1.x; af[5] = (_Float16)a1.y;
        af[6] = (_Float16)a1.z; af[7] = (_Float16)a1.w;
        #pragma unroll
        for (int t = 0; t < 4; ++t) {
            p2p[t] += b0[t].x*b0[t].x + b0[t].y*b0[t].y + b0[t].z*b0[t].z + b0[t].w*b0[t].w
                    + b1[t].x*b1[t].x + b1[t].y*b1[t].y + b1[t].z*b1[t].z + b1[t].w*b1[t].w;
            half8 bf;
            bf[0] = (_Float16)b0[t].x; bf[1] = (_Float16)b0[t].y;
            bf[2] = (_Float16)b0[t].z; bf[3] = (_Float16)b0[t].w;
            bf[4] = (_Float16)b1[t].x; bf[5] = (_Float16)b1[t].y;
            bf[6] = (_Float16)b1[t].z; bf[7] = (_Float16)b1[t].w;
            d[t] = __builtin_amdgcn_mfma_f32_16x16x32_f16(af, bf, d[t], 0, 0, 0);
        }
    }

    x2p += __shfl_xor(x2p, 16);
    x2p += __shfl_xor(x2p, 32);
    #pragma unroll
    for (int t = 0; t < 4; ++t) {
        p2p[t] += __shfl_xor(p2p[t], 16);
        p2p[t] += __shfl_xor(p2p[t], 32);
    }
    {
        float* dp = &dpart[wave][lane * DSTRIDE];
        #pragma unroll
        for (int t = 0; t < 4; ++t)
            *reinterpret_cast<float4*>(dp + t * 4) =
                make_float4(d[t][0], d[t][1], d[t][2], d[t][3]);
        if (quad == 0) {
            x2part[wave][l15] = x2p;
            #pragma unroll
            for (int t = 0; t < 4; ++t) p2part[wave][t * 16 + l15] = p2p[t];
        }
    }
    __syncthreads();

    const int y = rowBase >> 7;

    if (kq == 0) {
        floatx4 dsum[4];
        #pragma unroll
        for (int t = 0; t < 4; ++t) dsum[t] = (floatx4){0.f, 0.f, 0.f, 0.f};
        float x2r[4] = {0.f, 0.f, 0.f, 0.f};
        float p2c[4] = {0.f, 0.f, 0.f, 0.f};
        #pragma unroll
        for (int k2 = 0; k2 < KSPLIT; ++k2) {
            const int wv = m * 4 + k2;
            const float* src = &dpart[wv][lane * DSTRIDE];
            #pragma unroll
            for (int t = 0; t < 4; ++t) {
                const float4 vv = *reinterpret_cast<const float4*>(src + t * 4);
                dsum[t][0] += vv.x; dsum[t][1] += vv.y; dsum[t][2] += vv.z; dsum[t][3] += vv.w;
            }
            #pragma unroll
            for (int r = 0; r < 4; ++r) x2r[r] += x2part[wv][quad * 4 + r];
            #pragma unroll
            for (int t = 0; t < 4; ++t) p2c[t] += p2part[wv][t * 16 + l15];
        }
        float vc[4];
        #pragma unroll
        for (int t = 0; t < 4; ++t) vc[t] = V[t * 16 + l15];

        float lossAcc = 0.0f;
        #pragma unroll
        for (int r = 0; r < 4; ++r) {
            float lg[4];
            #pragma unroll
            for (int t = 0; t < 4; ++t)
                lg[t] = (2.0f * dsum[t][r] - x2r[r] - p2c[t]) / vc[t];
            float mx = fmaxf(fmaxf(lg[0], lg[1]), fmaxf(lg[2], lg[3]));
            #pragma unroll
            for (int dl = 1; dl <= 8; dl <<= 1) mx = fmaxf(mx, __shfl_xor(mx, dl));
            float s = expf(lg[0] - mx) + expf(lg[1] - mx)
                    + expf(lg[2] - mx) + expf(lg[3] - mx);
            #pragma unroll
            for (int dl = 1; dl <= 8; dl <<= 1) s += __shfl_xor(s, dl);
            const float lse = mx + logf(s);
            const int row = quad * 4 + r;
            #pragma unroll
            for (int t = 0; t < 4; ++t) {
                const int colc = t * 16 + l15;
                if (colc == y) lossAcc += w * (lse - lg[t]);
                atomicAdd(&predL[row * PSTRIDE + colc], w * expf(lg[t] - lse));
            }
        }
        #pragma unroll
        for (int dl = 1; dl <= 32; dl <<= 1) lossAcc += __shfl_xor(lossAcc, dl);
        if (lane == 0) atomicAdd(&lossL, lossAcc);
    }
    __syncthreads();

    if (wave == 0) {
        float cnt = 0.0f;
        #pragma unroll 1
        for (int r = 0; r < 16; ++r) {
            float bv = predL[r * PSTRIDE + lane];
            int   bc = lane;
            #pragma unroll
            for (int dl = 1; dl <= 32; dl <<= 1) {
                const float ov = __shfl_xor(bv, dl);
                const int   oc = __shfl_xor(bc, dl);
                if (ov > bv || (ov == bv && oc < bc)) { bv = ov; bc = oc; }
            }
            if (lane == 0 && bc == y) cnt += 1.0f;
        }
        if (lane == 0) {
            atomicAdd(&out[0], lossL * (1.0f / NROWS));
            atomicAdd(&out[1], cnt * (1.0f / NROWS));
        }
    }
}

extern "C" void kernel_launch(void* const* d_in, const int* in_sizes, int n_in,
                              void* d_out, int out_size, void* d_ws, size_t ws_size,
                              hipStream_t stream) {
    const float* Xtf = (const float*)d_in[0];
    const float* Ptf = (const float*)d_in[1];
    const float* Vtf = (const float*)d_in[2];
    const float* Xde = (const float*)d_in[3];
    const float* Pde = (const float*)d_in[4];
    const float* Vde = (const float*)d_in[5];
    const float* Xff = (const float*)d_in[6];
    const float* Pff = (const float*)d_in[7];
    const float* Vff = (const float*)d_in[8];
    float* out = (float*)d_out;

    if (ws_size >= (size_t)WS_NEED) {
        char* ws = (char*)d_ws;
        _Float16* W     = (_Float16*)(ws + OFF_W);
        float*    p2    = (float*)(ws + OFF_P2);
        float*    pd    = (float*)(ws + OFF_PD);
        float*    px2   = (float*)(ws + OFF_PX2);
        float*    lossP = (float*)(ws + OFF_LP);
        float*    cntP  = (float*)(ws + OFF_CP);

        hipMemsetAsync(p2, 0, 3 * NCLS * sizeof(float), stream);
        prep_protos<<<dim3(96), dim3(64), 0, stream>>>(Ptf, Pde, Pff, W, p2);
        fusion_main<<<dim3(3 * NRT * 2), dim3(256), 0, stream>>>(
            Xtf, Xde, Xff, W, pd, px2);
        finalize1<<<dim3(NRT), dim3(256), 0, stream>>>(
            pd, px2, p2, Vtf, Vde, Vff, lossP, cntP);
        finalize2<<<dim3(1), dim3(256), 0, stream>>>(lossP, cntP, out);
    } else {
        hipMemsetAsync(out, 0, 2 * sizeof(float), stream);
        fusion_loss_fallback<<<dim3(NROWS / 16), dim3(NWAVES * 64), 0, stream>>>(
            Xtf, Ptf, Vtf, Xde, Pde, Vde, Xff, Pff, Vff, out);
    }
}

// Round 9
// 153.604 us; speedup vs baseline: 1.0398x; 1.0206x over previous
//
#include <hip/hip_runtime.h>

// Fusion_loss: 3 modalities of Mahalanobis-distance softmax fusion.
// K=64 classes, Q=128 queries/class, DIM=1024. Rows M = 8192.
// logits_m[r][c] = -(||x_r||^2 - 2 x_r.p_c + ||p_c||^2) / var_c
// loss = mean_r sum_m w_m * (lse_m(r) - logits_m[r][y_r]),  y_r = r/128
// acc  = mean_r [argmax_c sum_m w_m softmax(logits_m)[r][c] == y_r]
//
// R9: R8's K-split cost a 12.6MB pd round-trip + a separate softmax pass
// + 2x W reads. Now: block = (m, row-tile) x FULL K, 4 waves (the R6
// small-block shape that beat R7's fat blocks), 8 double-buffered DMA
// chunks; per-m softmax + loss in-block; only fused-pred (6.3MB) leaves
// for an argmax-only finalize. 1536 blocks = 6/CU resident, 24 waves/CU,
// LDS 17.5KB. Bank conflicts (4cyc/b128, structural) accepted.

typedef _Float16 half8 __attribute__((ext_vector_type(8)));
typedef float    floatx4 __attribute__((ext_vector_type(4)));

#define NCLS   64
#define QPC    128
#define DIM    1024
#define NROWS  (NCLS * QPC)      // 8192
#define NRT    (NROWS / 16)      // 512 row tiles
#define UW2    132               // LDS row stride in words for 128-col chunk

// ws layout
#define OFF_W      0                          // f16 protos, B-frag units
#define W_BYTES    (3 * NCLS * DIM * 2)       // 393216
#define OFF_P2     W_BYTES                    // 768 B
#define OFF_PRED   397312                     // 4K-aligned
#define PRED_BYTES (3 * NROWS * NCLS * 4)     // 6291456
#define OFF_LP     (OFF_PRED + PRED_BYTES)    // 1536 floats
#define OFF_CP     (OFF_LP + 3 * NRT * 4)     // 512 floats
#define WS_NEED    (OFF_CP + NRT * 4)

__device__ __forceinline__ void dma4(const float* g, float* l) {
    __builtin_amdgcn_global_load_lds(
        (const __attribute__((address_space(1))) void*)g,
        (__attribute__((address_space(3))) void*)l,
        4, 0, 0);
}

// ---------------- prep: protos -> f16 B-frag layout + p2 ----------------
// Unit (m,kcg,t) = 1KB: lane (l15,quad) holds 8 halves = col t*16+l15,
// k = kcg*32 + quad*8 .. +8.  p2[m*64+c] via atomics.
__global__ __launch_bounds__(64) void prep_protos(
    const float* __restrict__ Ptf, const float* __restrict__ Pde,
    const float* __restrict__ Pff, _Float16* __restrict__ W,
    float* __restrict__ p2)
{
    const int m    = blockIdx.x >> 5;
    const int kcg  = blockIdx.x & 31;
    const int lane = threadIdx.x;
    const int l15  = lane & 15;
    const int quad = lane >> 4;
    const float* __restrict__ P = (m == 0) ? Ptf : (m == 1) ? Pde : Pff;

    #pragma unroll
    for (int t = 0; t < 4; ++t) {
        const float* src = P + (size_t)(t * 16 + l15) * DIM + kcg * 32 + quad * 8;
        const float4 b0 = *reinterpret_cast<const float4*>(src);
        const float4 b1 = *reinterpret_cast<const float4*>(src + 4);
        half8 h;
        h[0] = (_Float16)b0.x; h[1] = (_Float16)b0.y;
        h[2] = (_Float16)b0.z; h[3] = (_Float16)b0.w;
        h[4] = (_Float16)b1.x; h[5] = (_Float16)b1.y;
        h[6] = (_Float16)b1.z; h[7] = (_Float16)b1.w;
        *reinterpret_cast<half8*>(W + ((size_t)(m * 32 + kcg) * 4 + t) * 512 + lane * 8) = h;

        float s = b0.x*b0.x + b0.y*b0.y + b0.z*b0.z + b0.w*b0.w
                + b1.x*b1.x + b1.y*b1.y + b1.z*b1.z + b1.w*b1.w;
        s += __shfl_xor(s, 16);
        s += __shfl_xor(s, 32);
        if (quad == 0) atomicAdd(&p2[m * 64 + t * 16 + l15], s);
    }
}

// ---------------- main: full-K per-m GEMM + in-block softmax ----------------
// block = (m, row-tile); 4 waves; wave w = 16 rows x cols w*16..+15.
__global__ __launch_bounds__(256, 8) void fusion_main(
    const float* __restrict__ Xtf, const float* __restrict__ Xde,
    const float* __restrict__ Xff,
    const float* __restrict__ Vtf, const float* __restrict__ Vde,
    const float* __restrict__ Vff,
    const _Float16* __restrict__ W, const float* __restrict__ p2g,
    float* __restrict__ predOut,   // [3][8192][64] = wgt*softmax per m
    float* __restrict__ lossPart)  // [3*512]
{
    __shared__ float buf[2][16 * UW2];   // 16,896 B (DMA-only writes)
    __shared__ float x2s[16];
    __shared__ float mxW[4][16];
    __shared__ float sW[4][16];
    __shared__ float lossW[4];

    const int tid  = threadIdx.x;
    const int w    = tid >> 6;
    const int lane = tid & 63;
    const int l15  = lane & 15;
    const int quad = lane >> 4;
    const int b    = blockIdx.x;
    const int m    = b >> 9;          // /512
    const int rt   = b & 511;
    const int rowBase = rt * 16;

    const float* __restrict__ X = (m == 0) ? Xtf : (m == 1) ? Xde : Xff;
    const float* __restrict__ V = (m == 0) ? Vtf : (m == 1) ? Vde : Vff;
    const float  wgt = (m == 0) ? 1.0f : (m == 1) ? 0.8f : 0.6f;

    // per-lane global base for this wave's 4 rows; chunk c adds c*128
    const float* gb = X + (size_t)(rowBase + w * 4) * DIM + lane;

    floatx4 d = (floatx4){0.f, 0.f, 0.f, 0.f};
    float x2p = 0.0f;

    // prologue: stage chunk 0 into buf[0]
    #pragma unroll
    for (int r4 = 0; r4 < 4; ++r4) {
        dma4(gb + (size_t)r4 * DIM,      &buf[0][(w * 4 + r4) * UW2]);
        dma4(gb + (size_t)r4 * DIM + 64, &buf[0][(w * 4 + r4) * UW2 + 64]);
    }

    #pragma unroll
    for (int c = 0; c < 8; ++c) {
        __syncthreads();   // drains DMA(c); all waves done with compute(c-1)
        if (c < 7) {       // prefetch chunk c+1 into the other buffer
            const float* g1 = gb + (c + 1) * 128;
            float* lb = &buf[(c + 1) & 1][0];
            #pragma unroll
            for (int r4 = 0; r4 < 4; ++r4) {
                dma4(g1 + (size_t)r4 * DIM,      lb + (w * 4 + r4) * UW2);
                dma4(g1 + (size_t)r4 * DIM + 64, lb + (w * 4 + r4) * UW2 + 64);
            }
        }
        const float* tb = &buf[c & 1][0];
        #pragma unroll
        for (int kc = 0; kc < 4; ++kc) {
            const int off = l15 * UW2 + kc * 32 + quad * 8;
            const float4 a0 = *reinterpret_cast<const float4*>(tb + off);
            const float4 a1 = *reinterpret_cast<const float4*>(tb + off + 4);
            const int kcg = c * 4 + kc;
            const half8 bf = *reinterpret_cast<const half8*>(
                W + ((size_t)(m * 32 + kcg) * 4 + w) * 512 + lane * 8);

            if (w == 0)   // one wave computes x2 (rows shared by all waves)
                x2p += a0.x*a0.x + a0.y*a0.y + a0.z*a0.z + a0.w*a0.w
                     + a1.x*a1.x + a1.y*a1.y + a1.z*a1.z + a1.w*a1.w;

            half8 af;
            af[0] = (_Float16)a0.x; af[1] = (_Float16)a0.y;
            af[2] = (_Float16)a0.z; af[3] = (_Float16)a0.w;
            af[4] = (_Float16)a1.x; af[5] = (_Float16)a1.y;
            af[6] = (_Float16)a1.z; af[7] = (_Float16)a1.w;

            d = __builtin_amdgcn_mfma_f32_16x16x32_f16(af, bf, d, 0, 0, 0);
        }
    }

    // x2 of row l15 (w==0 wave holds the quad partials)
    if (w == 0) {
        x2p += __shfl_xor(x2p, 16);
        x2p += __shfl_xor(x2p, 32);
        if (quad == 0) x2s[l15] = x2p;
    }
    __syncthreads();

    // logits: row = quad*4+r, col = w*16+l15 (MFMA C/D layout)
    const int col = w * 16 + l15;
    const float vc  = V[col];
    const float p2c = p2g[m * 64 + col];
    float lg[4];
    #pragma unroll
    for (int r = 0; r < 4; ++r)
        lg[r] = (2.0f * d[r] - x2s[quad * 4 + r] - p2c) / vc;

    // per-wave 16-col max per row -> LDS
    #pragma unroll
    for (int r = 0; r < 4; ++r) {
        float mx = lg[r];
        #pragma unroll
        for (int dl = 1; dl <= 8; dl <<= 1) mx = fmaxf(mx, __shfl_xor(mx, dl));
        if (l15 == 0) mxW[w][quad * 4 + r] = mx;
    }
    __syncthreads();

    // 64-col max, per-wave exp-sum -> LDS
    float gmx[4];
    #pragma unroll
    for (int r = 0; r < 4; ++r) {
        const int row = quad * 4 + r;
        gmx[r] = fmaxf(fmaxf(mxW[0][row], mxW[1][row]),
                       fmaxf(mxW[2][row], mxW[3][row]));
        float s = expf(lg[r] - gmx[r]);
        #pragma unroll
        for (int dl = 1; dl <= 8; dl <<= 1) s += __shfl_xor(s, dl);
        if (l15 == 0) sW[w][quad * 4 + r] = s;
    }
    __syncthreads();

    // lse; loss at target col; per-m weighted softmax -> predOut
    const int y = rowBase >> 7;   // uniform across the block's 16 rows
    float lossAcc = 0.0f;
    #pragma unroll
    for (int r = 0; r < 4; ++r) {
        const int row = quad * 4 + r;
        const float lse = gmx[r] + logf(sW[0][row] + sW[1][row]
                                      + sW[2][row] + sW[3][row]);
        if (col == y) lossAcc += wgt * (lse - lg[r]);
        predOut[((size_t)m * NROWS + rowBase + row) * 64 + col] =
            wgt * expf(lg[r] - lse);
    }
    #pragma unroll
    for (int dl = 1; dl <= 32; dl <<= 1) lossAcc += __shfl_xor(lossAcc, dl);
    if (lane == 0) lossW[w] = lossAcc;
    __syncthreads();
    if (tid == 0) lossPart[b] = lossW[0] + lossW[1] + lossW[2] + lossW[3];
}

// ---------------- finalize1: fused argmax over 3-m pred ----------------
__global__ __launch_bounds__(256) void finalize1(
    const float* __restrict__ pred, float* __restrict__ cntPart)
{
    const int rt   = blockIdx.x;
    const int tid  = threadIdx.x;
    const int v    = tid >> 6;
    const int lane = tid & 63;

    float cnt = 0.0f;
    #pragma unroll
    for (int r4 = 0; r4 < 4; ++r4) {
        const int R = rt * 16 + v * 4 + r4;
        const int y = R >> 7;
        float p = pred[(size_t)R * 64 + lane]
                + pred[((size_t)NROWS + R) * 64 + lane]
                + pred[((size_t)2 * NROWS + R) * 64 + lane];
        float bv = p; int bc = lane;
        #pragma unroll
        for (int dl = 1; dl <= 32; dl <<= 1) {
            const float ov = __shfl_xor(bv, dl);
            const int   oc = __shfl_xor(bc, dl);
            if (ov > bv || (ov == bv && oc < bc)) { bv = ov; bc = oc; }
        }
        if (lane == 0 && bc == y) cnt += 1.0f;
    }
    #pragma unroll
    for (int dl = 1; dl <= 32; dl <<= 1) cnt += __shfl_xor(cnt, dl);
    __shared__ float sc[4];
    if (lane == 0) sc[v] = cnt;
    __syncthreads();
    if (tid == 0) cntPart[rt] = sc[0] + sc[1] + sc[2] + sc[3];
}

// ---------------- finalize2: scalar reduce ----------------
__global__ __launch_bounds__(256) void finalize2(
    const float* __restrict__ lossPart, const float* __restrict__ cntPart,
    float* __restrict__ out)
{
    const int tid  = threadIdx.x;
    const int lane = tid & 63;
    const int v    = tid >> 6;
    float l = 0.0f, c = 0.0f;
    for (int i = tid; i < 3 * NRT; i += 256) l += lossPart[i];
    for (int i = tid; i < NRT; i += 256)     c += cntPart[i];
    #pragma unroll
    for (int dl = 1; dl <= 32; dl <<= 1) {
        l += __shfl_xor(l, dl);
        c += __shfl_xor(c, dl);
    }
    __shared__ float sl[4], sc[4];
    if (lane == 0) { sl[v] = l; sc[v] = c; }
    __syncthreads();
    if (tid == 0) {
        out[0] = (sl[0] + sl[1] + sl[2] + sl[3]) * (1.0f / NROWS);
        out[1] = (sc[0] + sc[1] + sc[2] + sc[3]) * (1.0f / NROWS);
    }
}

// ---------------- fallback (R2 kernel, used only if ws too small) --------
#define NWAVES 12
#define KSPLIT 4
#define KSLICE (DIM / KSPLIT)
#define NITER  (KSLICE / 32)
#define DSTRIDE 17
#define PSTRIDE 65

__global__ __launch_bounds__(NWAVES * 64) void fusion_loss_fallback(
    const float* __restrict__ Xtf, const float* __restrict__ Ptf, const float* __restrict__ Vtf,
    const float* __restrict__ Xde, const float* __restrict__ Pde, const float* __restrict__ Vde,
    const float* __restrict__ Xff, const float* __restrict__ Pff, const float* __restrict__ Vff,
    float* __restrict__ out)
{
    __shared__ float dpart[NWAVES][64 * DSTRIDE];
    __shared__ float x2part[NWAVES][16];
    __shared__ float p2part[NWAVES][64];
    __shared__ float predL[16 * PSTRIDE];
    __shared__ float lossL;

    const int tid  = threadIdx.x;
    const int wave = tid >> 6;
    const int lane = tid & 63;
    const int l15  = lane & 15;
    const int quad = lane >> 4;
    const int m    = wave >> 2;
    const int kq   = wave & 3;
    const int rowBase = blockIdx.x * 16;

    for (int i = tid; i < 16 * PSTRIDE; i += NWAVES * 64) predL[i] = 0.0f;
    if (tid == 0) lossL = 0.0f;

    const float* __restrict__ X = (m == 0) ? Xtf : (m == 1) ? Xde : Xff;
    const float* __restrict__ P = (m == 0) ? Ptf : (m == 1) ? Pde : Pff;
    const float* __restrict__ V = (m == 0) ? Vtf : (m == 1) ? Vde : Vff;
    const float  w = (m == 0) ? 1.0f : (m == 1) ? 0.8f : 0.6f;

    floatx4 d[4];
    #pragma unroll
    for (int t = 0; t < 4; ++t) d[t] = (floatx4){0.f, 0.f, 0.f, 0.f};
    float x2p    = 0.0f;
    float p2p[4] = {0.f, 0.f, 0.f, 0.f};

    const float* xrow = X + (size_t)(rowBase + l15) * DIM + kq * KSLICE + quad * 8;
    const float* prow[4];
    #pragma unroll
    for (int t = 0; t < 4; ++t)
        prow[t] = P + (size_t)(t * 16 + l15) * DIM + kq * KSLICE + quad * 8;

    #pragma unroll 2
    for (int kc = 0; kc < NITER; ++kc) {
        const int ko = kc * 32;
        const float4 a0 = *reinterpret_cast<const float4*>(xrow + ko);
        const float4 a1 = *reinterpret_cast<const float4*>(xrow + ko + 4);
        float4 b0[4], b1[4];
        #pragma unroll
        for (int t = 0; t < 4; ++t) {
            b0[t] = *reinterpret_cast<const float4*>(prow[t] + ko);
            b1[t] = *reinterpret_cast<const float4*>(prow[t] + ko + 4);
        }
        x2p += a0.x*a0.x + a0.y*a0.y + a0.z*a0.z + a0.w*a0.w
             + a1.x*a1.x + a1.y*a1.y + a1.z*a1.z + a1.w*a1.w;
        half8 af;
        af[0] = (_Float16)a0.x; af[1] = (_Float16)a0.y;
        af[2] = (_Float16)a0.z; af[3] = (_Float16)a0.w;
        af[4] = (_Float16)a1.x; af[5] = (_Float16)a1.y;
        af[6] = (_Float16)a1.z; af[7] = (_Float16)a1.w;
        #pragma unroll
        for (int t = 0; t < 4; ++t) {
            p2p[t] += b0[t].x*b0[t].x + b0[t].y*b0[t].y + b0[t].z*b0[t].z + b0[t].w*b0[t].w
                    + b1[t].x*b1[t].x + b1[t].y*b1[t].y + b1[t].z*b1[t].z + b1[t].w*b1[t].w;
            half8 bf;
            bf[0] = (_Float16)b0[t].x; bf[1] = (_Float16)b0[t].y;
            bf[2] = (_Float16)b0[t].z; bf[3] = (_Float16)b0[t].w;
            bf[4] = (_Float16)b1[t].x; bf[5] = (_Float16)b1[t].y;
            bf[6] = (_Float16)b1[t].z; bf[7] = (_Float16)b1[t].w;
            d[t] = __builtin_amdgcn_mfma_f32_16x16x32_f16(af, bf, d[t], 0, 0, 0);
        }
    }

    x2p += __shfl_xor(x2p, 16);
    x2p += __shfl_xor(x2p, 32);
    #pragma unroll
    for (int t = 0; t < 4; ++t) {
        p2p[t] += __shfl_xor(p2p[t], 16);
        p2p[t] += __shfl_xor(p2p[t], 32);
    }
    {
        float* dp = &dpart[wave][lane * DSTRIDE];
        #pragma unroll
        for (int t = 0; t < 4; ++t)
            *reinterpret_cast<float4*>(dp + t * 4) =
                make_float4(d[t][0], d[t][1], d[t][2], d[t][3]);
        if (quad == 0) {
            x2part[wave][l15] = x2p;
            #pragma unroll
            for (int t = 0; t < 4; ++t) p2part[wave][t * 16 + l15] = p2p[t];
        }
    }
    __syncthreads();

    const int y = rowBase >> 7;

    if (kq == 0) {
        floatx4 dsum[4];
        #pragma unroll
        for (int t = 0; t < 4; ++t) dsum[t] = (floatx4){0.f, 0.f, 0.f, 0.f};
        float x2r[4] = {0.f, 0.f, 0.f, 0.f};
        float p2c[4] = {0.f, 0.f, 0.f, 0.f};
        #pragma unroll
        for (int k2 = 0; k2 < KSPLIT; ++k2) {
            const int wv = m * 4 + k2;
            const float* src = &dpart[wv][lane * DSTRIDE];
            #pragma unroll
            for (int t = 0; t < 4; ++t) {
                const float4 vv = *reinterpret_cast<const float4*>(src + t * 4);
                dsum[t][0] += vv.x; dsum[t][1] += vv.y; dsum[t][2] += vv.z; dsum[t][3] += vv.w;
            }
            #pragma unroll
            for (int r = 0; r < 4; ++r) x2r[r] += x2part[wv][quad * 4 + r];
            #pragma unroll
            for (int t = 0; t < 4; ++t) p2c[t] += p2part[wv][t * 16 + l15];
        }
        float vc[4];
        #pragma unroll
        for (int t = 0; t < 4; ++t) vc[t] = V[t * 16 + l15];

        float lossAcc = 0.0f;
        #pragma unroll
        for (int r = 0; r < 4; ++r) {
            float lg[4];
            #pragma unroll
            for (int t = 0; t < 4; ++t)
                lg[t] = (2.0f * dsum[t][r] - x2r[r] - p2c[t]) / vc[t];
            float mx = fmaxf(fmaxf(lg[0], lg[1]), fmaxf(lg[2], lg[3]));
            #pragma unroll
            for (int dl = 1; dl <= 8; dl <<= 1) mx = fmaxf(mx, __shfl_xor(mx, dl));
            float s = expf(lg[0] - mx) + expf(lg[1] - mx)
                    + expf(lg[2] - mx) + expf(lg[3] - mx);
            #pragma unroll
            for (int dl = 1; dl <= 8; dl <<= 1) s += __shfl_xor(s, dl);
            const float lse = mx + logf(s);
            const int row = quad * 4 + r;
            #pragma unroll
            for (int t = 0; t < 4; ++t) {
                const int colc = t * 16 + l15;
                if (colc == y) lossAcc += w * (lse - lg[t]);
                atomicAdd(&predL[row * PSTRIDE + colc], w * expf(lg[t] - lse));
            }
        }
        #pragma unroll
        for (int dl = 1; dl <= 32; dl <<= 1) lossAcc += __shfl_xor(lossAcc, dl);
        if (lane == 0) atomicAdd(&lossL, lossAcc);
    }
    __syncthreads();

    if (wave == 0) {
        float cnt = 0.0f;
        #pragma unroll 1
        for (int r = 0; r < 16; ++r) {
            float bv = predL[r * PSTRIDE + lane];
            int   bc = lane;
            #pragma unroll
            for (int dl = 1; dl <= 32; dl <<= 1) {
                const float ov = __shfl_xor(bv, dl);
                const int   oc = __shfl_xor(bc, dl);
                if (ov > bv || (ov == bv && oc < bc)) { bv = ov; bc = oc; }
            }
            if (lane == 0 && bc == y) cnt += 1.0f;
        }
        if (lane == 0) {
            atomicAdd(&out[0], lossL * (1.0f / NROWS));
            atomicAdd(&out[1], cnt * (1.0f / NROWS));
        }
    }
}

extern "C" void kernel_launch(void* const* d_in, const int* in_sizes, int n_in,
                              void* d_out, int out_size, void* d_ws, size_t ws_size,
                              hipStream_t stream) {
    const float* Xtf = (const float*)d_in[0];
    const float* Ptf = (const float*)d_in[1];
    const float* Vtf = (const float*)d_in[2];
    const float* Xde = (const float*)d_in[3];
    const float* Pde = (const float*)d_in[4];
    const float* Vde = (const float*)d_in[5];
    const float* Xff = (const float*)d_in[6];
    const float* Pff = (const float*)d_in[7];
    const float* Vff = (const float*)d_in[8];
    float* out = (float*)d_out;

    if (ws_size >= (size_t)WS_NEED) {
        char* ws = (char*)d_ws;
        _Float16* W     = (_Float16*)(ws + OFF_W);
        float*    p2    = (float*)(ws + OFF_P2);
        float*    pred  = (float*)(ws + OFF_PRED);
        float*    lossP = (float*)(ws + OFF_LP);
        float*    cntP  = (float*)(ws + OFF_CP);

        hipMemsetAsync(p2, 0, 3 * NCLS * sizeof(float), stream);
        prep_protos<<<dim3(96), dim3(64), 0, stream>>>(Ptf, Pde, Pff, W, p2);
        fusion_main<<<dim3(3 * NRT), dim3(256), 0, stream>>>(
            Xtf, Xde, Xff, Vtf, Vde, Vff, W, p2, pred, lossP);
        finalize1<<<dim3(NRT), dim3(256), 0, stream>>>(pred, cntP);
        finalize2<<<dim3(1), dim3(256), 0, stream>>>(lossP, cntP, out);
    } else {
        hipMemsetAsync(out, 0, 2 * sizeof(float), stream);
        fusion_loss_fallback<<<dim3(NROWS / 16), dim3(NWAVES * 64), 0, stream>>>(
            Xtf, Ptf, Vtf, Xde, Pde, Vde, Xff, Pff, Vff, out);
    }
}